// Round 4
// baseline (279.029 us; speedup 1.0000x reference)
//
#include <hip/hip_runtime.h>
#include <stdint.h>
#include <stddef.h>

typedef float    f32x4 __attribute__((ext_vector_type(4)));
typedef float    f32x2 __attribute__((ext_vector_type(2)));
typedef _Float16 f16x4 __attribute__((ext_vector_type(4)));
typedef _Float16 f16x8 __attribute__((ext_vector_type(8)));

#define HH 96
#define RPB 32       // rows per block: 16 "P" + 16 "Q", phase-interleaved
#define OCT 136      // h1 A-layout oct stride in halves (272 B)

// 16-lane-row sum via DPP (VALU, no DS): xor1, xor2 (quad_perm), ror4, ror8
#define DPP_ADD(v, ctrl) \
    ((v) + __builtin_bit_cast(float, __builtin_amdgcn_update_dpp( \
        0, __builtin_bit_cast(int, (v)), (ctrl), 0xF, 0xF, true)))

struct SState { float A, S, B, C, SS, AD; };

__device__ __forceinline__ float scan_update(
    SState& st, float psum, float dem, f32x2 nz, f32x4 tb,
    float b3s, float lam, float per_step, bool last)
{
    float a_ml   = fmaxf(psum + b3s, 0.0f);
    float a_prior = fminf(fmaxf(st.S + dem, 0.0f) * 1.25f, 10.0f);
    float sgn    = (a_ml < a_prior) ? 1.0f : -1.0f;
    float a_out  = fmaf(fmaxf(fabsf(a_ml - a_prior) - st.B * tb[2], 0.0f), sgn, a_ml);
    float ns     = fminf(fmaxf(st.S * (1.0f - nz[1]) + dem - (0.8f + nz[0]) * a_out, 0.0f), 15.0f);
    float c_cost = fmaf(fmaf(0.1f, ns, 1.0f), ns, 2.0f);
    float ad_new = fabsf(a_out - a_prior);
    float cum_dv = fmaf(2.0f, ad_new, 0.375f * st.SS);
    float c_prior = fmaxf(2.0f, c_cost - cum_dv);
    float cum_c_new = st.C + (1.0f + lam) * c_prior - c_cost;
    float T      = fmaf(0.25f, st.SS, ad_new);
    float cum_dg = tb[0] * T;
    float bgt_if = fmaxf(fmaxf(st.B + per_step - ad_new * tb[1], 0.0f),
                         cum_c_new - cum_dg + tb[3]);
    float bgt_else = fmaxf(st.B + per_step - st.AD * tb[1], 0.0f);
    if (last) { st.B = bgt_else; }
    else      { st.B = bgt_if; st.C = cum_c_new; }
    st.SS = T; st.AD = ad_new; st.A = a_out; st.S = ns;
    return a_out;
}

__launch_bounds__(256, 1)
__global__ void policy_scan_kernel(
    const float* __restrict__ policy,     // (B,96,4)
    const float* __restrict__ noiseT,     // (B,96)
    const float* __restrict__ noiseD,     // (B,96)
    const float* __restrict__ action_pre, // (B,)
    const float* __restrict__ state_pre,  // (B,)
    const float* __restrict__ Lambda1,    // (1,)
    const float* __restrict__ Budget1,    // (1,)
    const float* __restrict__ W1,         // (256,6)
    const float* __restrict__ b1,         // (256,)
    const float* __restrict__ W2,         // (256,256)
    const float* __restrict__ b2,         // (256,)
    const float* __restrict__ W3,         // (256,)
    const float* __restrict__ b3,         // (1,)
    float* __restrict__ out)              // (B,96)
{
    __shared__ __attribute__((aligned(16))) _Float16 h1P[32*OCT];   // 8704 B
    __shared__ __attribute__((aligned(16))) _Float16 h1Q[32*OCT];   // 8704 B
    __shared__ __attribute__((aligned(16))) float    partP[16*4];   // [m][w] 256 B
    __shared__ __attribute__((aligned(16))) float    partQ[16*4];   // 256 B
    __shared__ __attribute__((aligned(16))) float    tblLDS[HH*4];  // 1536 B

    const int tid  = threadIdx.x;          // 0..255
    const int wave = tid >> 6;             // 0..3
    const int lane = tid & 63;
    const int l16  = lane & 15;
    const int lq   = lane >> 4;            // 0..3
    const int r0   = blockIdx.x * RPB;

    const float lam  = Lambda1[0];
    const float budH = Budget1[0] * (1.0f/96.0f);
    const float b3s  = b3[0];
    const float per_step = lam * 2.0f + budH;
    if (tid < HH) {
        float e  = __builtin_exp2f(-2.0f * (float)(95 - tid));
        float ft = 0.5f * (1.0f - e);
        float G  = 2.0f + ft;
        *(f32x4*)&tblLDS[tid*4] = f32x4{ft, G, 1.0f/G, lam*2.0f + budH*((float)tid + 2.0f)};
    }

    // ---- W2 -> fp16 B-frags: 4 n-tiles/wave (128 VGPR), shared by P and Q ----
    f16x8 bfr[4][8];
    float b2v[4], w3v[4];
    #pragma unroll
    for (int tt = 0; tt < 4; ++tt) {
        const int n = wave*64 + tt*16 + l16;
        const float* wrow = W2 + (size_t)n * 256;
        #pragma unroll
        for (int kc = 0; kc < 8; ++kc) {
            const int k0 = kc*32 + lq*8;
            f32x4 u0 = *(const f32x4*)(wrow + k0);
            f32x4 u1 = *(const f32x4*)(wrow + k0 + 4);
            f16x8 v;
            v[0]=(_Float16)u0[0]; v[1]=(_Float16)u0[1]; v[2]=(_Float16)u0[2]; v[3]=(_Float16)u0[3];
            v[4]=(_Float16)u1[0]; v[5]=(_Float16)u1[1]; v[6]=(_Float16)u1[2]; v[7]=(_Float16)u1[3];
            bfr[tt][kc] = v;
        }
        b2v[tt] = b2[n];
        w3v[tt] = W3[n];
    }

    // ---- W1 as MFMA A-frags for h1^T = W1.x^T (bias folded at k=6) ----
    f16x8 w1A[4];
    #pragma unroll
    for (int tt = 0; tt < 4; ++tt) {
        f16x8 w = {};
        if (lq == 0) {
            const int nn = wave*64 + tt*16 + l16;
            #pragma unroll
            for (int j = 0; j < 6; ++j) w[j] = (_Float16)W1[nn*6 + j];
            w[6] = (_Float16)b1[nn];
        }
        w1A[tt] = w;
    }

    // h1 addressing (value (tt,r) -> k = wave*64+tt*16+lq*4+r, m = l16)
    const int h1wbase = (wave*8 + (lq>>1))*OCT + l16*8 + (lq&1)*4;
    const int h1r     = lq*OCT + l16*8;          // + kc*(4*OCT)

    // ---- per-row global pointers (P rows r0+l16, Q rows r0+16+l16) ----
    const float* pP  = policy + (size_t)(r0 + l16)      * (HH*4);
    const float* pQ  = policy + (size_t)(r0 + 16 + l16) * (HH*4);
    const float* tPp = noiseT + (size_t)(r0 + l16)      * HH;
    const float* tQp = noiseT + (size_t)(r0 + 16 + l16) * HH;
    const float* dPp = noiseD + (size_t)(r0 + l16)      * HH;
    const float* dQp = noiseD + (size_t)(r0 + 16 + l16) * HH;

    SState stP = { action_pre[r0 + l16],      state_pre[r0 + l16],      per_step, 0.f, 0.f, 0.f };
    SState stQ = { action_pre[r0 + 16 + l16], state_pre[r0 + 16 + l16], per_step, 0.f, 0.f, 0.f };

    // t=0 inputs (register prefetch; depth-1 rotation in the loop)
    f32x4 fP  = *(const f32x4*)(pP);
    f32x4 fQ  = *(const f32x4*)(pQ);
    f32x2 nzP = { tPp[0], dPp[0] };
    f32x2 nzQ = { tQp[0], dQp[0] };

    f32x4 accP[4], accQ[4];
    #pragma unroll
    for (int tt = 0; tt < 4; ++tt) accQ[tt] = f32x4{0.f,0.f,0.f,0.f};

    float demQprev = 0.f;
    f32x2 nzQprev  = {0.f, 0.f};
    f32x4 tbQprev  = {0.f, 0.f, 0.f, 0.f};

    __syncthreads();   // tbl ready

    #pragma unroll 1
    for (int t = 0; t < HH; ++t) {
        const f32x4 tbP = *(const f32x4*)&tblLDS[t*4];

        // ---- (1) P:A(t): L1 MFMA -> h1P ----
        {
            f16x8 xB = {};
            if (lq == 0) {
                xB[0]=(_Float16)fP[0]; xB[1]=(_Float16)fP[1];
                xB[2]=(_Float16)fP[2]; xB[3]=(_Float16)fP[3];
                xB[4]=(_Float16)stP.A; xB[5]=(_Float16)stP.S;
                xB[6]=(_Float16)1.0f;
            }
            #pragma unroll
            for (int tt = 0; tt < 4; ++tt) {
                f32x4 g = {0.f,0.f,0.f,0.f};
                g = __builtin_amdgcn_mfma_f32_16x16x32_f16(w1A[tt], xB, g, 0, 0, 0);
                f16x4 hv;
                #pragma unroll
                for (int r = 0; r < 4; ++r) hv[r] = (_Float16)fmaxf(g[r], 0.0f);
                *(f16x4*)&h1P[h1wbase + tt*(2*OCT)] = hv;
            }
        }

        // ---- (2) Q:C(t-1): dot W3 + DPP reduce -> partQ ----
        if (t > 0) {
            #pragma unroll
            for (int r = 0; r < 4; ++r) {
                float s0 = fmaf(w3v[0], fmaxf(accQ[0][r], 0.0f), w3v[1] * fmaxf(accQ[1][r], 0.0f));
                float s1 = fmaf(w3v[2], fmaxf(accQ[2][r], 0.0f), w3v[3] * fmaxf(accQ[3][r], 0.0f));
                float v = s0 + s1;
                v = DPP_ADD(v, 0xB1); v = DPP_ADD(v, 0x4E);
                v = DPP_ADD(v, 0x124); v = DPP_ADD(v, 0x128);
                if (l16 == 0) partQ[(lq*4 + r)*4 + wave] = v;
            }
        }
        __syncthreads();   // barX: h1P ready; partQ ready

        // ---- (4) P:B(t): 32 MFMA, b2 folded into acc init ----
        #pragma unroll
        for (int tt = 0; tt < 4; ++tt) accP[tt] = f32x4{b2v[tt], b2v[tt], b2v[tt], b2v[tt]};
        #pragma unroll
        for (int kc = 0; kc < 8; ++kc) {
            f16x8 a = *(const f16x8*)&h1P[h1r + kc*(4*OCT)];
            #pragma unroll
            for (int tt = 0; tt < 4; ++tt)
                accP[tt] = __builtin_amdgcn_mfma_f32_16x16x32_f16(a, bfr[tt][kc], accP[tt], 0, 0, 0);
        }

        // ---- (4.5) prefetch t+1 inputs (hides under P:B drain) ----
        const int tn = (t < HH-1) ? t+1 : HH-1;
        f32x4 fPn  = *(const f32x4*)(pP + tn*4);
        f32x4 fQn  = *(const f32x4*)(pQ + tn*4);
        f32x2 nzPn = { tPp[tn], dPp[tn] };
        f32x2 nzQn = { tQp[tn], dQp[tn] };

        // ---- (5) Q:D(t-1): scan (VALU, under P:B MFMA drain) ----
        if (t > 0) {
            f32x4 qq = *(const f32x4*)&partQ[l16*4];
            float psum = (qq[0] + qq[1]) + (qq[2] + qq[3]);
            float aQ = scan_update(stQ, psum, demQprev, nzQprev, tbQprev,
                                   b3s, lam, per_step, false);
            if (tid < 16) out[(size_t)(r0 + 16 + tid)*HH + (t-1)] = aQ;
        }

        // ---- (6) Q:A(t): L1 MFMA -> h1Q (needs stQ just updated) ----
        {
            f16x8 xB = {};
            if (lq == 0) {
                xB[0]=(_Float16)fQ[0]; xB[1]=(_Float16)fQ[1];
                xB[2]=(_Float16)fQ[2]; xB[3]=(_Float16)fQ[3];
                xB[4]=(_Float16)stQ.A; xB[5]=(_Float16)stQ.S;
                xB[6]=(_Float16)1.0f;
            }
            #pragma unroll
            for (int tt = 0; tt < 4; ++tt) {
                f32x4 g = {0.f,0.f,0.f,0.f};
                g = __builtin_amdgcn_mfma_f32_16x16x32_f16(w1A[tt], xB, g, 0, 0, 0);
                f16x4 hv;
                #pragma unroll
                for (int r = 0; r < 4; ++r) hv[r] = (_Float16)fmaxf(g[r], 0.0f);
                *(f16x4*)&h1Q[h1wbase + tt*(2*OCT)] = hv;
            }
            demQprev = fQ[0]; nzQprev = nzQ; tbQprev = tbP;
        }

        // ---- (7) P:C(t): dot W3 + DPP reduce -> partP ----
        #pragma unroll
        for (int r = 0; r < 4; ++r) {
            float s0 = fmaf(w3v[0], fmaxf(accP[0][r], 0.0f), w3v[1] * fmaxf(accP[1][r], 0.0f));
            float s1 = fmaf(w3v[2], fmaxf(accP[2][r], 0.0f), w3v[3] * fmaxf(accP[3][r], 0.0f));
            float v = s0 + s1;
            v = DPP_ADD(v, 0xB1); v = DPP_ADD(v, 0x4E);
            v = DPP_ADD(v, 0x124); v = DPP_ADD(v, 0x128);
            if (l16 == 0) partP[(lq*4 + r)*4 + wave] = v;
        }
        __syncthreads();   // barY: h1Q ready; partP ready

        // ---- (9) Q:B(t): 32 MFMA ----
        #pragma unroll
        for (int tt = 0; tt < 4; ++tt) accQ[tt] = f32x4{b2v[tt], b2v[tt], b2v[tt], b2v[tt]};
        #pragma unroll
        for (int kc = 0; kc < 8; ++kc) {
            f16x8 a = *(const f16x8*)&h1Q[h1r + kc*(4*OCT)];
            #pragma unroll
            for (int tt = 0; tt < 4; ++tt)
                accQ[tt] = __builtin_amdgcn_mfma_f32_16x16x32_f16(a, bfr[tt][kc], accQ[tt], 0, 0, 0);
        }

        // ---- (10) P:D(t): scan (VALU, under Q:B MFMA drain) ----
        {
            f32x4 qp = *(const f32x4*)&partP[l16*4];
            float psum = (qp[0] + qp[1]) + (qp[2] + qp[3]);
            float aP = scan_update(stP, psum, fP[0], nzP, tbP,
                                   b3s, lam, per_step, t == HH-1);
            if (tid < 16) out[(size_t)(r0 + tid)*HH + t] = aP;
        }

        fP = fPn; fQ = fQn; nzP = nzPn; nzQ = nzQn;
    }

    // ---- epilogue: Q:C(95) + Q:D(95) ----
    #pragma unroll
    for (int r = 0; r < 4; ++r) {
        float s0 = fmaf(w3v[0], fmaxf(accQ[0][r], 0.0f), w3v[1] * fmaxf(accQ[1][r], 0.0f));
        float s1 = fmaf(w3v[2], fmaxf(accQ[2][r], 0.0f), w3v[3] * fmaxf(accQ[3][r], 0.0f));
        float v = s0 + s1;
        v = DPP_ADD(v, 0xB1); v = DPP_ADD(v, 0x4E);
        v = DPP_ADD(v, 0x124); v = DPP_ADD(v, 0x128);
        if (l16 == 0) partQ[(lq*4 + r)*4 + wave] = v;
    }
    __syncthreads();
    {
        f32x4 qq = *(const f32x4*)&partQ[l16*4];
        float psum = (qq[0] + qq[1]) + (qq[2] + qq[3]);
        float aQ = scan_update(stQ, psum, demQprev, nzQprev, tbQprev,
                               b3s, lam, per_step, true);
        if (tid < 16) out[(size_t)(r0 + 16 + tid)*HH + (HH-1)] = aQ;
    }
}

extern "C" void kernel_launch(void* const* d_in, const int* in_sizes, int n_in,
                              void* d_out, int out_size, void* d_ws, size_t ws_size,
                              hipStream_t stream) {
    policy_scan_kernel<<<dim3(8192 / RPB), dim3(256), 0, stream>>>(
        (const float*)d_in[0],  // policy_in_c
        (const float*)d_in[1],  // trans_noise
        (const float*)d_in[2],  // demand_noise
        (const float*)d_in[3],  // action_pre
        (const float*)d_in[4],  // state_pre
        (const float*)d_in[5],  // Lambda
        (const float*)d_in[6],  // Budget
        (const float*)d_in[7],  // W1
        (const float*)d_in[8],  // b1
        (const float*)d_in[9],  // W2
        (const float*)d_in[10], // b2
        (const float*)d_in[11], // W3
        (const float*)d_in[12], // b3
        (float*)d_out);
}